// Round 1
// baseline (49.000 us; speedup 1.0000x reference)
//
#include <hip/hip_runtime.h>

#define NB 16
#define HH 1024
#define WW 1024
#define TW 64
#define TH 32
#define RW (TW + 4)   // 68
#define RH (TH + 4)   // 36

__global__ __launch_bounds__(256)
void aes_kernel(const float* __restrict__ mask,
                const float* __restrict__ blur_strength,
                const float* __restrict__ edge_sensitivity,
                const float* __restrict__ final_threshold,
                float* __restrict__ out)
{
    __shared__ float raw[RH][RW];

    const int b      = blockIdx.z;
    const int tile_x = blockIdx.x * TW;
    const int tile_y = blockIdx.y * TH;
    const float* m = mask + (size_t)b * (HH * WW);

    // ---- stage raw tile + halo(2) into LDS, zero-padded (SAME conv) ----
    for (int i = threadIdx.x; i < RH * RW; i += 256) {
        int ly = i / RW, lx = i - ly * RW;
        int gy = tile_y + ly - 2;
        int gx = tile_x + lx - 2;
        float v = 0.0f;
        if ((unsigned)gy < (unsigned)HH && (unsigned)gx < (unsigned)WW)
            v = m[(size_t)gy * WW + gx];
        raw[ly][lx] = v;
    }
    __syncthreads();

    // per-sample params, double precision (match float64 np reference)
    const double bf   = (double)blur_strength[b] / 3.0;     // blur_factor
    const double ethr = 0.5 * (double)edge_sensitivity[b];  // edge threshold
    const double fthr = (double)final_threshold[b];
    const double w25  = (double)(1.0f / 25.0f);             // AVG5 weight (fp32 const -> f64)

    // each thread: one column (tx), 8 consecutive output rows starting at r0
    const int tx = threadIdx.x & 63;
    const int r0 = (threadIdx.x >> 6) * 8;

    // rolling rings over raw rows: h5 = 5-wide hsum (cols tx..tx+4),
    // h3 = 3-wide hsum (cols tx+1..tx+3), cc = center col (tx+2)
    double h5[5], h3[5], cc[5];

    #pragma unroll
    for (int k = 0; k < 4; ++k) {
        double a0 = (double)raw[r0 + k][tx + 0];
        double a1 = (double)raw[r0 + k][tx + 1];
        double a2 = (double)raw[r0 + k][tx + 2];
        double a3 = (double)raw[r0 + k][tx + 3];
        double a4 = (double)raw[r0 + k][tx + 4];
        h5[k] = ((a0 + a1) + (a2 + a3)) + a4;
        h3[k] = (a1 + a2) + a3;
        cc[k] = a2;
    }

    float* op = out + (size_t)b * (HH * WW);

    #pragma unroll
    for (int r = 0; r < 8; ++r) {
        const int ry = r0 + r + 4;        // new raw row entering the window
        const int k  = (r + 4) % 5;       // compile-time after unroll
        double a0 = (double)raw[ry][tx + 0];
        double a1 = (double)raw[ry][tx + 1];
        double a2 = (double)raw[ry][tx + 2];
        double a3 = (double)raw[ry][tx + 3];
        double a4 = (double)raw[ry][tx + 4];
        h5[k] = ((a0 + a1) + (a2 + a3)) + a4;
        h3[k] = (a1 + a2) + a3;
        cc[k] = a2;

        // window now holds raw rows (r0+r) .. (r0+r+4); row (r0+j) at ring j%5
        double sum25 = (h5[0] + h5[1]) + (h5[2] + h5[3]) + h5[4];
        double sum9  = h3[(r + 1) % 5] + h3[(r + 2) % 5] + h3[(r + 3) % 5];
        double center = cc[(r + 2) % 5];

        double lap    = 9.0 * center - sum9;          // 8c - (sum9 - c)
        double edges  = fabs(lap);
        double sbase  = sum25 * w25;                  // 5x5 box blur
        double smooth = center * (1.0 - bf) + sbase * bf;
        double result = (edges > ethr) ? smooth : center;

        op[(size_t)(tile_y + r0 + r) * WW + tile_x + tx] =
            (result > fthr) ? 1.0f : 0.0f;
    }
}

extern "C" void kernel_launch(void* const* d_in, const int* in_sizes, int n_in,
                              void* d_out, int out_size, void* d_ws, size_t ws_size,
                              hipStream_t stream) {
    const float* mask = (const float*)d_in[0];
    const float* bs   = (const float*)d_in[1];
    const float* es   = (const float*)d_in[2];
    const float* ft   = (const float*)d_in[3];
    float* out = (float*)d_out;

    dim3 grid(WW / TW, HH / TH, NB);
    aes_kernel<<<grid, 256, 0, stream>>>(mask, bs, es, ft, out);
}

// Round 2
// 46.978 us; speedup vs baseline: 1.0430x; 1.0430x over previous
//
#include <hip/hip_runtime.h>

#define NB 16
#define HH 1024
#define WW 1024
#define TW 64
#define TH 32
#define RW (TW + 4)   // 68
#define RH (TH + 4)   // 36

#define EPS1 1e-4f    // edge-threshold confidence margin (f32 err bound ~6e-6)
#define EPS2 1e-4f    // final-threshold confidence margin (f32 err bound ~2e-6)

__global__ __launch_bounds__(256)
void aes_kernel(const float* __restrict__ mask,
                const float* __restrict__ blur_strength,
                const float* __restrict__ edge_sensitivity,
                const float* __restrict__ final_threshold,
                float* __restrict__ out)
{
    __shared__ float raw[RH][RW];

    const int b      = blockIdx.z;
    const int tile_x = blockIdx.x * TW;
    const int tile_y = blockIdx.y * TH;
    const float* m = mask + (size_t)b * (HH * WW);

    // ---- stage raw tile + halo(2) into LDS, zero-padded (SAME conv) ----
    for (int i = threadIdx.x; i < RH * RW; i += 256) {
        int ly = i / RW, lx = i - ly * RW;
        int gy = tile_y + ly - 2;
        int gx = tile_x + lx - 2;
        float v = 0.0f;
        if ((unsigned)gy < (unsigned)HH && (unsigned)gx < (unsigned)WW)
            v = m[(size_t)gy * WW + gx];
        raw[ly][lx] = v;
    }
    __syncthreads();

    // per-sample params — fp32 (ethr, fthr, w25 are EXACT in f32)
    const float bsf   = blur_strength[b];
    const float esf   = edge_sensitivity[b];
    const float fthr  = final_threshold[b];
    const float ethr  = 0.5f * esf;            // exact
    const float bff   = bsf / 3.0f;            // ~1 ulp vs f64 — covered by EPS2
    const float onembf = 1.0f - bff;
    const float w25f  = 1.0f / 25.0f;          // same constant the reference uses

    // fp64 params for the fallback path (identical to the proven R1 kernel)
    const double bfd   = (double)bsf / 3.0;
    const double ethrd = 0.5 * (double)esf;
    const double fthrd = (double)fthr;
    const double w25d  = (double)(1.0f / 25.0f);

    // each thread: one column (tx), 8 consecutive output rows starting at r0
    const int tx = threadIdx.x & 63;
    const int r0 = (threadIdx.x >> 6) * 8;

    // rolling rings over raw rows: h5 = 5-wide hsum, h3 = 3-wide hsum, cc = center
    float h5[5], h3[5], cc[5];

    #pragma unroll
    for (int k = 0; k < 4; ++k) {
        float a0 = raw[r0 + k][tx + 0];
        float a1 = raw[r0 + k][tx + 1];
        float a2 = raw[r0 + k][tx + 2];
        float a3 = raw[r0 + k][tx + 3];
        float a4 = raw[r0 + k][tx + 4];
        h5[k] = ((a0 + a1) + (a2 + a3)) + a4;
        h3[k] = (a1 + a2) + a3;
        cc[k] = a2;
    }

    float* op = out + (size_t)b * (HH * WW);

    #pragma unroll
    for (int r = 0; r < 8; ++r) {
        const int ry = r0 + r + 4;        // new raw row entering the window
        const int k  = (r + 4) % 5;       // compile-time after unroll
        float a0 = raw[ry][tx + 0];
        float a1 = raw[ry][tx + 1];
        float a2 = raw[ry][tx + 2];
        float a3 = raw[ry][tx + 3];
        float a4 = raw[ry][tx + 4];
        h5[k] = ((a0 + a1) + (a2 + a3)) + a4;
        h3[k] = (a1 + a2) + a3;
        cc[k] = a2;

        // window holds raw rows (r0+r)..(r0+r+4); row (r0+j) lives at ring j%5
        float sum25  = (h5[0] + h5[1]) + (h5[2] + h5[3]) + h5[4];
        float sum9   = h3[(r + 1) % 5] + h3[(r + 2) % 5] + h3[(r + 3) % 5];
        float center = cc[(r + 2) % 5];

        float edges  = fabsf(9.0f * center - sum9);
        float sbase  = sum25 * w25f;
        float smooth = center * onembf + sbase * bff;

        bool  isedge = edges > ethr;
        // confidence: edge decision clear; if edge taken, smooth vs fthr clear.
        // (no-edge branch compares EXACT center to EXACT fthr — always safe)
        bool conf = fabsf(edges - ethr) > EPS1;
        float res = isedge ? smooth : center;
        if (isedge) conf = conf && (fabsf(smooth - fthr) > EPS2);

        float o = (res > fthr) ? 1.0f : 0.0f;

        if (!conf) {
            // f64 recompute (exact same math as the R1 kernel that scored absmax 0)
            double s25 = 0.0, s9 = 0.0;
            #pragma unroll
            for (int dy = 0; dy < 5; ++dy) {
                #pragma unroll
                for (int dx = 0; dx < 5; ++dx) {
                    double v = (double)raw[r0 + r + dy][tx + dx];
                    s25 += v;
                    if (dy >= 1 && dy <= 3 && dx >= 1 && dx <= 3) s9 += v;
                }
            }
            double c      = (double)raw[r0 + r + 2][tx + 2];
            double edgesd = fabs(9.0 * c - s9);
            double sbd    = s25 * w25d;
            double smd    = c * (1.0 - bfd) + sbd * bfd;
            double resd   = (edgesd > ethrd) ? smd : c;
            o = (resd > fthrd) ? 1.0f : 0.0f;
        }

        op[(size_t)(tile_y + r0 + r) * WW + tile_x + tx] = o;
    }
}

extern "C" void kernel_launch(void* const* d_in, const int* in_sizes, int n_in,
                              void* d_out, int out_size, void* d_ws, size_t ws_size,
                              hipStream_t stream) {
    const float* mask = (const float*)d_in[0];
    const float* bs   = (const float*)d_in[1];
    const float* es   = (const float*)d_in[2];
    const float* ft   = (const float*)d_in[3];
    float* out = (float*)d_out;

    dim3 grid(WW / TW, HH / TH, NB);
    aes_kernel<<<grid, 256, 0, stream>>>(mask, bs, es, ft, out);
}

// Round 3
// 43.420 us; speedup vs baseline: 1.1285x; 1.0819x over previous
//
#include <hip/hip_runtime.h>

#define NB 16
#define HH 1024
#define WW 1024
#define TW 64          // tile width (output)
#define TH 128         // tile height (output)
#define LC 72          // LDS cols staged: global x in [tile_x-4, tile_x+68)
#define LR 132         // LDS rows staged: global y in [tile_y-2, tile_y+130)
#define N4 (LR * (LC / 4))   // float4 staging ops = 2376

#define EPS1 2e-4f     // edge-threshold confidence margin (f32 err bound ~4e-6)
#define EPS2 1e-4f     // final-threshold confidence margin (f32 err bound ~4e-6)

// Cold exact-path: recompute one pixel in f64 (identical math to the R1
// kernel that scored absmax 0.0 against the np/f64 reference).
__device__ __noinline__ float aes_exact(const float (*raw)[LC], int lr, int lc,
                                        float bsf, float esf, float fthr)
{
    const double bfd   = (double)bsf / 3.0;
    const double ethrd = 0.5 * (double)esf;
    const double fthrd = (double)fthr;
    const double w25d  = (double)(1.0f / 25.0f);

    double s25 = 0.0, s9 = 0.0;
    for (int dy = 0; dy < 5; ++dy)
        for (int dx = 0; dx < 5; ++dx) {
            double v = (double)raw[lr + dy][lc + dx];
            s25 += v;
            if (dy >= 1 && dy <= 3 && dx >= 1 && dx <= 3) s9 += v;
        }
    double c      = (double)raw[lr + 2][lc + 2];
    double edges  = fabs(9.0 * c - s9);
    double sbase  = s25 * w25d;
    double smooth = c * (1.0 - bfd) + sbase * bfd;
    double result = (edges > ethrd) ? smooth : c;
    return (result > fthrd) ? 1.0f : 0.0f;
}

__global__ __launch_bounds__(256)
void aes_kernel(const float* __restrict__ mask,
                const float* __restrict__ blur_strength,
                const float* __restrict__ edge_sensitivity,
                const float* __restrict__ final_threshold,
                float* __restrict__ out)
{
    __shared__ float raw[LR][LC];   // row stride 288B: banks shift 8/row, 2-way max

    const int b      = blockIdx.z;
    const int tile_x = blockIdx.x * TW;
    const int tile_y = blockIdx.y * TH;
    const float* m = mask + (size_t)b * (HH * WW);

    // ---- stage tile + halo as float4; every float4 fully in or out of bounds
    for (int i = threadIdx.x; i < N4; i += 256) {
        int row = i / (LC / 4);
        int c4  = i - row * (LC / 4);
        int gy  = tile_y - 2 + row;
        int gx  = tile_x - 4 + 4 * c4;     // multiple of 4 -> 16B aligned
        float4 v = make_float4(0.f, 0.f, 0.f, 0.f);
        if ((unsigned)gy < (unsigned)HH && (unsigned)gx < (unsigned)WW)
            v = *(const float4*)(m + (size_t)gy * WW + gx);
        *(float4*)&raw[row][4 * c4] = v;
    }
    __syncthreads();

    const float bsf    = blur_strength[b];
    const float esf    = edge_sensitivity[b];
    const float fthr   = final_threshold[b];
    const float ethr   = 0.5f * esf;          // exact in f32
    const float bff    = bsf / 3.0f;
    const float onembf = 1.0f - bff;
    const float w25f   = 1.0f / 25.0f;

    // thread -> 4 cols x 8 rows micro-tile
    const int tx  = threadIdx.x & 15;         // col group
    const int ty  = threadIdx.x >> 4;         // row group
    const int lr0 = ty * 8;                   // LDS row of first window row
    const int lc0 = 4 * tx + 2;               // LDS col of (x0-2); byte 16*tx+8

    // rolling ring over 5 raw rows; [ring][col]
    float h5[5][4], h3[5][4], cc[5][4];

    // loads 8 contiguous floats a0..a7 = global cols x0-2 .. x0+5 of one row,
    // builds rolling horizontal sums for the 4 output columns
#define LOADROW(ROWIDX, K)                                                  \
    {                                                                       \
        const float* rp = &raw[(ROWIDX)][0];                                \
        float2 u0 = *(const float2*)(rp + lc0);        /* 8B aligned  */    \
        float4 u1 = *(const float4*)(rp + lc0 + 2);    /* 16B aligned */    \
        float2 u2 = *(const float2*)(rp + lc0 + 6);    /* 8B aligned  */    \
        float a0 = u0.x, a1 = u0.y, a2 = u1.x, a3 = u1.y;                   \
        float a4 = u1.z, a5 = u1.w, a6 = u2.x, a7 = u2.y;                   \
        float s5 = ((a0 + a1) + (a2 + a3)) + a4;                            \
        h5[(K)][0] = s5; s5 = s5 - a0 + a5;                                 \
        h5[(K)][1] = s5; s5 = s5 - a1 + a6;                                 \
        h5[(K)][2] = s5; s5 = s5 - a2 + a7;                                 \
        h5[(K)][3] = s5;                                                    \
        float s3 = (a1 + a2) + a3;                                          \
        h3[(K)][0] = s3; s3 = s3 - a1 + a4;                                 \
        h3[(K)][1] = s3; s3 = s3 - a2 + a5;                                 \
        h3[(K)][2] = s3; s3 = s3 - a3 + a6;                                 \
        h3[(K)][3] = s3;                                                    \
        cc[(K)][0] = a2; cc[(K)][1] = a3; cc[(K)][2] = a4; cc[(K)][3] = a5; \
    }

    #pragma unroll
    for (int k = 0; k < 4; ++k)
        LOADROW(lr0 + k, k)

    float* op = out + (size_t)b * (HH * WW)
                    + (size_t)(tile_y + ty * 8) * WW + tile_x + 4 * tx;

    #pragma unroll
    for (int r = 0; r < 8; ++r) {
        LOADROW(lr0 + r + 4, (r + 4) % 5)
        const int i0 = r % 5, i1 = (r + 1) % 5, i2 = (r + 2) % 5;
        const int i3 = (r + 3) % 5, i4 = (r + 4) % 5;

        float4 ov;
        #pragma unroll
        for (int c = 0; c < 4; ++c) {
            float sum25  = ((h5[i0][c] + h5[i1][c]) + (h5[i2][c] + h5[i3][c])) + h5[i4][c];
            float s9     = h3[i1][c] + h3[i2][c] + h3[i3][c];
            float center = cc[i2][c];

            float edges  = fabsf(9.0f * center - s9);
            float sbase  = sum25 * w25f;
            float smooth = center * onembf + sbase * bff;

            bool isedge = edges > ethr;
            // no-edge branch compares EXACT center vs EXACT fthr -> always safe
            bool conf = (fabsf(edges - ethr) > EPS1) &&
                        (!isedge || (fabsf(smooth - fthr) > EPS2));
            float res = isedge ? smooth : center;
            float o   = (res > fthr) ? 1.0f : 0.0f;

            if (!conf)
                o = aes_exact(raw, lr0 + r, lc0 + c, bsf, esf, fthr);

            (&ov.x)[c] = o;     // c is compile-time after unroll
        }
        *(float4*)(op + (size_t)r * WW) = ov;
    }
#undef LOADROW
}

extern "C" void kernel_launch(void* const* d_in, const int* in_sizes, int n_in,
                              void* d_out, int out_size, void* d_ws, size_t ws_size,
                              hipStream_t stream) {
    const float* mask = (const float*)d_in[0];
    const float* bs   = (const float*)d_in[1];
    const float* es   = (const float*)d_in[2];
    const float* ft   = (const float*)d_in[3];
    float* out = (float*)d_out;

    dim3 grid(WW / TW, HH / TH, NB);   // 16 x 8 x 16 = 2048 blocks
    aes_kernel<<<grid, 256, 0, stream>>>(mask, bs, es, ft, out);
}

// Round 4
// 37.743 us; speedup vs baseline: 1.2982x; 1.1504x over previous
//
#include <hip/hip_runtime.h>

#define NB 16
#define HH 1024
#define WW 1024
#define TW 128         // tile width  (output)
#define TH 32          // tile height (output)
#define LC 136         // staged cols: global x in [tile_x-4, tile_x+132)
#define LR 36          // staged rows: global y in [tile_y-2, tile_y+34)
#define N4 (LR * (LC / 4))   // float4 staging ops = 36*34 = 1224

#define EPS1 2e-4f     // edge-threshold confidence margin (f32 err bound ~4e-6)
#define EPS2 1e-4f     // final-threshold confidence margin (f32 err bound ~4e-6)

// Cold exact-path: recompute one pixel in f64 (identical math to the R1
// kernel that scored absmax 0.0 against the np/f64 reference).
__device__ __noinline__ float aes_exact(const float (*raw)[LC], int lr, int lc,
                                        float bsf, float esf, float fthr)
{
    const double bfd   = (double)bsf / 3.0;
    const double ethrd = 0.5 * (double)esf;
    const double fthrd = (double)fthr;
    const double w25d  = (double)(1.0f / 25.0f);

    double s25 = 0.0, s9 = 0.0;
    for (int dy = 0; dy < 5; ++dy)
        for (int dx = 0; dx < 5; ++dx) {
            double v = (double)raw[lr + dy][lc + dx];
            s25 += v;
            if (dy >= 1 && dy <= 3 && dx >= 1 && dx <= 3) s9 += v;
        }
    double c      = (double)raw[lr + 2][lc + 2];
    double edges  = fabs(9.0 * c - s9);
    double sbase  = s25 * w25d;
    double smooth = c * (1.0 - bfd) + sbase * bfd;
    double result = (edges > ethrd) ? smooth : c;
    return (result > fthrd) ? 1.0f : 0.0f;
}

__global__ __launch_bounds__(256)
void aes_kernel(const float* __restrict__ mask,
                const float* __restrict__ blur_strength,
                const float* __restrict__ edge_sensitivity,
                const float* __restrict__ final_threshold,
                float* __restrict__ out)
{
    __shared__ float raw[LR][LC];   // 19,584 B -> 8 blocks/CU (100% occupancy)

    const int b      = blockIdx.z;
    const int tile_x = blockIdx.x * TW;
    const int tile_y = blockIdx.y * TH;
    const float* m = mask + (size_t)b * (HH * WW);

    // ---- stage tile + halo as float4; every float4 fully in or out of bounds
    for (int i = threadIdx.x; i < N4; i += 256) {
        int row = i / (LC / 4);
        int c4  = i - row * (LC / 4);
        int gy  = tile_y - 2 + row;
        int gx  = tile_x - 4 + 4 * c4;     // multiple of 4 -> 16B aligned
        float4 v = make_float4(0.f, 0.f, 0.f, 0.f);
        if ((unsigned)gy < (unsigned)HH && (unsigned)gx < (unsigned)WW)
            v = *(const float4*)(m + (size_t)gy * WW + gx);
        *(float4*)&raw[row][4 * c4] = v;
    }
    __syncthreads();

    const float bsf    = blur_strength[b];
    const float esf    = edge_sensitivity[b];
    const float fthr   = final_threshold[b];
    const float ethr   = 0.5f * esf;          // exact in f32
    const float bff    = bsf / 3.0f;
    const float onembf = 1.0f - bff;
    const float w25f   = 1.0f / 25.0f;

    // thread -> 4 cols x 4 rows micro-tile
    const int tx  = threadIdx.x & 31;         // col group (32 groups * 4 = 128)
    const int ty  = threadIdx.x >> 5;         // row group (8 groups * 4 = 32)
    const int lr0 = ty * 4;                   // LDS row of first window row
    const int lc0 = 4 * tx + 2;               // LDS col of (x0-2)

    // rolling ring over 5 raw rows; [ring][col]
    float h5[5][4], h3[5][4], cc[5][4];

    // loads 8 contiguous floats a0..a7 = global cols x0-2 .. x0+5 of one row,
    // builds rolling horizontal sums for the 4 output columns
#define LOADROW(ROWIDX, K)                                                  \
    {                                                                       \
        const float* rp = &raw[(ROWIDX)][0];                                \
        float2 u0 = *(const float2*)(rp + lc0);        /* 8B aligned  */    \
        float4 u1 = *(const float4*)(rp + lc0 + 2);    /* 16B aligned */    \
        float2 u2 = *(const float2*)(rp + lc0 + 6);    /* 8B aligned  */    \
        float a0 = u0.x, a1 = u0.y, a2 = u1.x, a3 = u1.y;                   \
        float a4 = u1.z, a5 = u1.w, a6 = u2.x, a7 = u2.y;                   \
        float s5 = ((a0 + a1) + (a2 + a3)) + a4;                            \
        h5[(K)][0] = s5; s5 = s5 - a0 + a5;                                 \
        h5[(K)][1] = s5; s5 = s5 - a1 + a6;                                 \
        h5[(K)][2] = s5; s5 = s5 - a2 + a7;                                 \
        h5[(K)][3] = s5;                                                    \
        float s3 = (a1 + a2) + a3;                                          \
        h3[(K)][0] = s3; s3 = s3 - a1 + a4;                                 \
        h3[(K)][1] = s3; s3 = s3 - a2 + a5;                                 \
        h3[(K)][2] = s3; s3 = s3 - a3 + a6;                                 \
        h3[(K)][3] = s3;                                                    \
        cc[(K)][0] = a2; cc[(K)][1] = a3; cc[(K)][2] = a4; cc[(K)][3] = a5; \
    }

    #pragma unroll
    for (int k = 0; k < 4; ++k)
        LOADROW(lr0 + k, k)

    float* op = out + (size_t)b * (HH * WW)
                    + (size_t)(tile_y + ty * 4) * WW + tile_x + 4 * tx;

    #pragma unroll
    for (int r = 0; r < 4; ++r) {
        LOADROW(lr0 + r + 4, (r + 4) % 5)
        const int i0 = r % 5, i1 = (r + 1) % 5, i2 = (r + 2) % 5;
        const int i3 = (r + 3) % 5, i4 = (r + 4) % 5;

        float4 ov;
        #pragma unroll
        for (int c = 0; c < 4; ++c) {
            float sum25  = ((h5[i0][c] + h5[i1][c]) + (h5[i2][c] + h5[i3][c])) + h5[i4][c];
            float s9     = h3[i1][c] + h3[i2][c] + h3[i3][c];
            float center = cc[i2][c];

            float edges  = fabsf(9.0f * center - s9);
            float sbase  = sum25 * w25f;
            float smooth = center * onembf + sbase * bff;

            bool isedge = edges > ethr;
            // no-edge branch compares EXACT center vs EXACT fthr -> always safe
            bool conf = (fabsf(edges - ethr) > EPS1) &&
                        (!isedge || (fabsf(smooth - fthr) > EPS2));
            float res = isedge ? smooth : center;
            float o   = (res > fthr) ? 1.0f : 0.0f;

            if (!conf)
                o = aes_exact(raw, lr0 + r, lc0 + c, bsf, esf, fthr);

            (&ov.x)[c] = o;     // c is compile-time after unroll
        }
        *(float4*)(op + (size_t)r * WW) = ov;
    }
#undef LOADROW
}

extern "C" void kernel_launch(void* const* d_in, const int* in_sizes, int n_in,
                              void* d_out, int out_size, void* d_ws, size_t ws_size,
                              hipStream_t stream) {
    const float* mask = (const float*)d_in[0];
    const float* bs   = (const float*)d_in[1];
    const float* es   = (const float*)d_in[2];
    const float* ft   = (const float*)d_in[3];
    float* out = (float*)d_out;

    dim3 grid(WW / TW, HH / TH, NB);   // 8 x 32 x 16 = 4096 blocks
    aes_kernel<<<grid, 256, 0, stream>>>(mask, bs, es, ft, out);
}